// Round 5
// baseline (348.887 us; speedup 1.0000x reference)
//
#include <hip/hip_runtime.h>
#include <math.h>

typedef float f4 __attribute__((ext_vector_type(4)));

#define TOKENS 16384
#define DIM    4096
#define NE     64
#define KTOP   8
#define BM     64
#define BK     64
#define NGRP   4                 // in-block K-split groups
#define KRANGE (DIM / NGRP)      // 1024 K per group
#define NTILE  (KRANGE / BK)     // 16 tiles per group
#define NT     1024              // 16 waves/block
#define NBLK   (TOKENS / BM)     // 256 blocks = 1 block/CU, 16 waves/CU

// K1: gate GEMM (in-block K-split-4) + softmax + top-8.
// Each 256-thread group = round-1 proven core: 4x4 register tile, BK=64,
// XOR-swizzled LDS (element [kk][m] at kk*64 + (((m>>2)^(kk>>2))&15)*4 + (m&3)),
// register prefetch of the next K-tile. Groups share nothing but barriers.
// NOTE: no min-waves arg in __launch_bounds__ — (NT,4) clamps VGPR to 64 and
// spills the register tile (rounds 2 & 4: WRITE_SIZE 0.5-3.4 GB). LDS=128KB
// already caps residency at 1 block/CU = 4 waves/SIMD; ~108 VGPR fits that.
__global__ __launch_bounds__(NT) void gate_topk_kernel(
    const float* __restrict__ x, const float* __restrict__ W,
    const float* __restrict__ bias, float* __restrict__ idx_out,
    float* __restrict__ val_out, float* __restrict__ blocksums)
{
    __shared__ float smem[NGRP][2][BK * BM];   // [g][0]=As (later P[g]), [g][1]=Bs; 128 KB
    __shared__ float bsum[16];

    const int tid = threadIdx.x;
    const int g   = tid >> 8;      // K-split group 0..3
    const int gt  = tid & 255;     // thread-in-group
    // staging mapping (within group)
    const int kq = gt & 15;        // f4 index along K
    const int mg = gt >> 4;        // base row, rows mg+16s
    // compute mapping: 16x16 thread grid, 4x4 register tile
    const int tx = gt & 15;
    const int ty = gt >> 4;
    const int tm = ty << 2;
    const int tn = tx << 2;
    const int row0 = blockIdx.x * BM;

    float* As = smem[g][0];
    float* Bs = smem[g][1];

    const int kbase = g * KRANGE;
    const float* xa0 = x + (size_t)(row0 + mg) * DIM + kbase + (kq << 2);
    const float* wb0 = W + (size_t)mg * DIM + kbase + (kq << 2);

    float acc[4][4] = {};
    f4 fa[4], fb[4];
#pragma unroll
    for (int s = 0; s < 4; ++s) {
        fa[s] = *(const f4*)(xa0 + (size_t)(16 * s) * DIM);
        fb[s] = *(const f4*)(wb0 + (size_t)(16 * s) * DIM);
    }

    for (int kt = 0; kt < NTILE; ++kt) {
        __syncthreads();   // previous tile's reads done (all groups in lockstep)
#pragma unroll
        for (int s = 0; s < 4; ++s) {
            const int m  = mg + (s << 4);
            const int c4 = ((m >> 2) ^ kq) & 15;
            const int base = (kq << 2) * BM + (c4 << 2) + (m & 3);
#pragma unroll
            for (int j = 0; j < 4; ++j) {
                As[base + (j << 6)] = fa[s][j];
                Bs[base + (j << 6)] = fb[s][j];
            }
        }
        __syncthreads();
        if (kt + 1 < NTILE) {   // prefetch next tile into regs (HBM hides under FMAs)
            const int ko = (kt + 1) * BK;
#pragma unroll
            for (int s = 0; s < 4; ++s) {
                fa[s] = *(const f4*)(xa0 + (size_t)(16 * s) * DIM + ko);
                fb[s] = *(const f4*)(wb0 + (size_t)(16 * s) * DIM + ko);
            }
        }
        // two-level accumulation: fresh sub-acc per K-tile (top-k tie-safe precision)
        float acct[4][4] = {};
#pragma unroll
        for (int kk = 0; kk < BK; ++kk) {
            const int kq2 = kk >> 2;
            const f4 a4 = *(const f4*)&As[kk * BM + (((ty ^ kq2) & 15) << 2)];
            const f4 b4 = *(const f4*)&Bs[kk * NE + (((tx ^ kq2) & 15) << 2)];
#pragma unroll
            for (int i = 0; i < 4; ++i)
#pragma unroll
                for (int j = 0; j < 4; ++j)
                    acct[i][j] = fmaf(a4[i], b4[j], acct[i][j]);
        }
#pragma unroll
        for (int i = 0; i < 4; ++i)
#pragma unroll
            for (int j = 0; j < 4; ++j)
                acc[i][j] += acct[i][j];
    }

    // RACE FIX (round-3 tripwire): the final COMPUTE's ds_reads of As must
    // complete block-wide before any thread overwrites As with partial logits.
    __syncthreads();

    // ---- write partial logits P[g][m][e] over our own As region
#pragma unroll
    for (int i = 0; i < 4; ++i) {
        f4 v = { acc[i][0], acc[i][1], acc[i][2], acc[i][3] };
        *(f4*)&As[(tm + i) * NE + tn] = v;
    }
    __syncthreads();

    // ---- epilogue: wave wv handles tokens 4wv..4wv+3; lane = expert
    const int wv   = tid >> 6;
    const int lane = tid & 63;
    const float bv = bias[lane];
    float wsum = 0.0f;
#pragma unroll
    for (int tt = 0; tt < 4; ++tt) {
        const int t = wv * 4 + tt;
        const int token = row0 + t;
        const float logit = smem[0][0][t * NE + lane] + smem[1][0][t * NE + lane]
                          + smem[2][0][t * NE + lane] + smem[3][0][t * NE + lane] + bv;
        float mx = logit;
#pragma unroll
        for (int off = 32; off > 0; off >>= 1)
            mx = fmaxf(mx, __shfl_xor(mx, off, 64));
        const float p = expf(logit - mx);
        float s = p;
#pragma unroll
        for (int off = 32; off > 0; off >>= 1)
            s += __shfl_xor(s, off, 64);           // identical tree on all lanes
        const float rs = 1.0f / s;
        float pv = p;
#pragma unroll
        for (int j = 0; j < KTOP; ++j) {
            float v = pv; int e = lane;
#pragma unroll
            for (int off = 1; off < 64; off <<= 1) {   // argmax, lower idx wins ties
                const float v2 = __shfl_xor(v, off, 64);
                const int   e2 = __shfl_xor(e, off, 64);
                if (v2 > v || (v2 == v && e2 < e)) { v = v2; e = e2; }
            }
            const float val = v * rs;
            if (lane == j) {
                idx_out[token * KTOP + j] = (float)e;   // d_out read back as flat f32
                val_out[token * KTOP + j] = val;        // raw; normalized by K2
            }
            if (lane == e) pv = -1.0f;
            wsum += val;                                // uniform across lanes
        }
    }
    if (lane == 0) bsum[wv] = wsum;
    __syncthreads();
    if (tid == 0) {
        float t = 0.0f;
#pragma unroll
        for (int i = 0; i < 16; ++i) t += bsum[i];
        blocksums[blockIdx.x] = t;
    }
}

// K2: weights = vals / sum(all vals). Every thread computes the same serial sum
// of 256 partials (uniform -> scalarized, deterministic), then divides in place.
__global__ __launch_bounds__(256) void scale_kernel(
    const float* __restrict__ blocksums, float* __restrict__ vals)
{
    float total = 0.0f;
    for (int i = 0; i < NBLK; ++i) total += blocksums[i];
    const int i = blockIdx.x * blockDim.x + threadIdx.x;
    vals[i] = vals[i] / total;
}

extern "C" void kernel_launch(void* const* d_in, const int* in_sizes, int n_in,
                              void* d_out, int out_size, void* d_ws, size_t ws_size,
                              hipStream_t stream)
{
    const float* x = (const float*)d_in[0];
    const float* W = (const float*)d_in[1];
    const float* b = (const float*)d_in[2];
    float* idx_out = (float*)d_out;
    float* val_out = idx_out + (size_t)TOKENS * KTOP;
    float* blocksums = (float*)d_ws;

    gate_topk_kernel<<<NBLK, NT, 0, stream>>>(x, W, b, idx_out, val_out, blocksums);
    scale_kernel<<<(TOKENS * KTOP) / 256, 256, 0, stream>>>(blocksums, val_out);
}

// Round 6
// 348.593 us; speedup vs baseline: 1.0008x; 1.0008x over previous
//
#include <hip/hip_runtime.h>
#include <math.h>

typedef float f4 __attribute__((ext_vector_type(4)));

#define TOKENS 16384
#define DIM    4096
#define NE     64
#define KTOP   8
#define BM     64
#define BK     64
#define NGRP   4                 // in-block K-split groups
#define KRANGE (DIM / NGRP)      // 1024 K per group
#define NTILE  (KRANGE / BK)     // 16 tiles per group
#define NT     1024              // 16 waves/block
#define NBLK   (TOKENS / BM)     // 256 blocks = 1 block/CU, 16 waves/CU

// K1: gate GEMM (in-block K-split-4) + softmax + top-8.
// Each 256-thread group = round-1 proven core: 4x4 register tile, BK=64,
// XOR-swizzled LDS (element [kk][m] at kk*64 + (((m>>2)^(kk>>2))&15)*4 + (m&3)),
// register prefetch of the next K-tile. Groups share nothing but barriers.
//
// VGPR-clamp fix (rounds 2/4/5 post-mortem): for 1024-thread blocks the
// compiler's occupancy heuristic targets 8 waves/EU -> caps VGPR at 64 and
// spills ~2KB/thread (WRITE_SIZE 0.5-3.4 GB, VALUBusy ~21%). LDS=128KB already
// limits residency to 1 block/CU = 4 waves/EU, so pin waves_per_eu to exactly
// 4 -> VGPR budget 128 >= the ~108 this core needs. One change vs round 5.
__global__ __launch_bounds__(NT)
__attribute__((amdgpu_waves_per_eu(4, 4)))
void gate_topk_kernel(
    const float* __restrict__ x, const float* __restrict__ W,
    const float* __restrict__ bias, float* __restrict__ idx_out,
    float* __restrict__ val_out, float* __restrict__ blocksums)
{
    __shared__ float smem[NGRP][2][BK * BM];   // [g][0]=As (later P[g]), [g][1]=Bs; 128 KB
    __shared__ float bsum[16];

    const int tid = threadIdx.x;
    const int g   = tid >> 8;      // K-split group 0..3
    const int gt  = tid & 255;     // thread-in-group
    // staging mapping (within group)
    const int kq = gt & 15;        // f4 index along K
    const int mg = gt >> 4;        // base row, rows mg+16s
    // compute mapping: 16x16 thread grid, 4x4 register tile
    const int tx = gt & 15;
    const int ty = gt >> 4;
    const int tm = ty << 2;
    const int tn = tx << 2;
    const int row0 = blockIdx.x * BM;

    float* As = smem[g][0];
    float* Bs = smem[g][1];

    const int kbase = g * KRANGE;
    const float* xa0 = x + (size_t)(row0 + mg) * DIM + kbase + (kq << 2);
    const float* wb0 = W + (size_t)mg * DIM + kbase + (kq << 2);

    float acc[4][4] = {};
    f4 fa[4], fb[4];
#pragma unroll
    for (int s = 0; s < 4; ++s) {
        fa[s] = *(const f4*)(xa0 + (size_t)(16 * s) * DIM);
        fb[s] = *(const f4*)(wb0 + (size_t)(16 * s) * DIM);
    }

    for (int kt = 0; kt < NTILE; ++kt) {
        __syncthreads();   // previous tile's reads done (all groups in lockstep)
#pragma unroll
        for (int s = 0; s < 4; ++s) {
            const int m  = mg + (s << 4);
            const int c4 = ((m >> 2) ^ kq) & 15;
            const int base = (kq << 2) * BM + (c4 << 2) + (m & 3);
#pragma unroll
            for (int j = 0; j < 4; ++j) {
                As[base + (j << 6)] = fa[s][j];
                Bs[base + (j << 6)] = fb[s][j];
            }
        }
        __syncthreads();
        if (kt + 1 < NTILE) {   // prefetch next tile into regs (HBM hides under FMAs)
            const int ko = (kt + 1) * BK;
#pragma unroll
            for (int s = 0; s < 4; ++s) {
                fa[s] = *(const f4*)(xa0 + (size_t)(16 * s) * DIM + ko);
                fb[s] = *(const f4*)(wb0 + (size_t)(16 * s) * DIM + ko);
            }
        }
        // two-level accumulation: fresh sub-acc per K-tile (top-k tie-safe precision)
        float acct[4][4] = {};
#pragma unroll
        for (int kk = 0; kk < BK; ++kk) {
            const int kq2 = kk >> 2;
            const f4 a4 = *(const f4*)&As[kk * BM + (((ty ^ kq2) & 15) << 2)];
            const f4 b4 = *(const f4*)&Bs[kk * NE + (((tx ^ kq2) & 15) << 2)];
#pragma unroll
            for (int i = 0; i < 4; ++i)
#pragma unroll
                for (int j = 0; j < 4; ++j)
                    acct[i][j] = fmaf(a4[i], b4[j], acct[i][j]);
        }
#pragma unroll
        for (int i = 0; i < 4; ++i)
#pragma unroll
            for (int j = 0; j < 4; ++j)
                acc[i][j] += acct[i][j];
    }

    // RACE FIX (round-3 tripwire): the final COMPUTE's ds_reads of As must
    // complete block-wide before any thread overwrites As with partial logits.
    __syncthreads();

    // ---- write partial logits P[g][m][e] over our own As region
#pragma unroll
    for (int i = 0; i < 4; ++i) {
        f4 v = { acc[i][0], acc[i][1], acc[i][2], acc[i][3] };
        *(f4*)&As[(tm + i) * NE + tn] = v;
    }
    __syncthreads();

    // ---- epilogue: wave wv handles tokens 4wv..4wv+3; lane = expert
    const int wv   = tid >> 6;
    const int lane = tid & 63;
    const float bv = bias[lane];
    float wsum = 0.0f;
#pragma unroll
    for (int tt = 0; tt < 4; ++tt) {
        const int t = wv * 4 + tt;
        const int token = row0 + t;
        const float logit = smem[0][0][t * NE + lane] + smem[1][0][t * NE + lane]
                          + smem[2][0][t * NE + lane] + smem[3][0][t * NE + lane] + bv;
        float mx = logit;
#pragma unroll
        for (int off = 32; off > 0; off >>= 1)
            mx = fmaxf(mx, __shfl_xor(mx, off, 64));
        const float p = expf(logit - mx);
        float s = p;
#pragma unroll
        for (int off = 32; off > 0; off >>= 1)
            s += __shfl_xor(s, off, 64);           // identical tree on all lanes
        const float rs = 1.0f / s;
        float pv = p;
#pragma unroll
        for (int j = 0; j < KTOP; ++j) {
            float v = pv; int e = lane;
#pragma unroll
            for (int off = 1; off < 64; off <<= 1) {   // argmax, lower idx wins ties
                const float v2 = __shfl_xor(v, off, 64);
                const int   e2 = __shfl_xor(e, off, 64);
                if (v2 > v || (v2 == v && e2 < e)) { v = v2; e = e2; }
            }
            const float val = v * rs;
            if (lane == j) {
                idx_out[token * KTOP + j] = (float)e;   // d_out read back as flat f32
                val_out[token * KTOP + j] = val;        // raw; normalized by K2
            }
            if (lane == e) pv = -1.0f;
            wsum += val;                                // uniform across lanes
        }
    }
    if (lane == 0) bsum[wv] = wsum;
    __syncthreads();
    if (tid == 0) {
        float t = 0.0f;
#pragma unroll
        for (int i = 0; i < 16; ++i) t += bsum[i];
        blocksums[blockIdx.x] = t;
    }
}

// K2: weights = vals / sum(all vals). Every thread computes the same serial sum
// of 256 partials (uniform -> scalarized, deterministic), then divides in place.
__global__ __launch_bounds__(256) void scale_kernel(
    const float* __restrict__ blocksums, float* __restrict__ vals)
{
    float total = 0.0f;
    for (int i = 0; i < NBLK; ++i) total += blocksums[i];
    const int i = blockIdx.x * blockDim.x + threadIdx.x;
    vals[i] = vals[i] / total;
}

extern "C" void kernel_launch(void* const* d_in, const int* in_sizes, int n_in,
                              void* d_out, int out_size, void* d_ws, size_t ws_size,
                              hipStream_t stream)
{
    const float* x = (const float*)d_in[0];
    const float* W = (const float*)d_in[1];
    const float* b = (const float*)d_in[2];
    float* idx_out = (float*)d_out;
    float* val_out = idx_out + (size_t)TOKENS * KTOP;
    float* blocksums = (float*)d_ws;

    gate_topk_kernel<<<NBLK, NT, 0, stream>>>(x, W, b, idx_out, val_out, blocksums);
    scale_kernel<<<(TOKENS * KTOP) / 256, 256, 0, stream>>>(blocksums, val_out);
}